// Round 6
// baseline (511.795 us; speedup 1.0000x reference)
//
#include <hip/hip_runtime.h>
#include <math.h>

#define WD 128

// ---- bf16 round-to-nearest-even, low 16 bits ----
__device__ __forceinline__ unsigned bf16_rne(float f) {
    unsigned u = __float_as_uint(f);
    return (u + 0x7FFFu + ((u >> 16) & 1u)) >> 16;
}
__device__ __forceinline__ float bf16_lo(unsigned p) {  // low bf16 -> f32
    return __uint_as_float(p << 16);
}
__device__ __forceinline__ float bf16_hi(unsigned p) {  // high bf16 -> f32
    return __uint_as_float(p & 0xFFFF0000u);
}

// ============ fused: [blocks < gb]  y = x @ We[:128]; pack {bf16 x, bf16 y}
//                     [blocks >= gb] degree count (2 edges/thread) ============
__global__ __launch_bounds__(512) void k_gemm_count(const float* __restrict__ x,
                                                    const float* __restrict__ We,
                                                    unsigned* __restrict__ xy,
                                                    const int* __restrict__ ei,
                                                    int* __restrict__ cnt,
                                                    int n, int E, int gb) {
    if ((int)blockIdx.x < gb) {
        __shared__ float xs[16][WD];
        int j = threadIdx.x & 127;
        int q4 = threadIdx.x >> 7;  // 0..3
        int row0 = blockIdx.x * 16;
        for (int t = threadIdx.x; t < 16 * WD; t += 512) {
            int r = t >> 7, c = t & 127;
            int gr = row0 + r;
            xs[r][c] = (gr < n) ? x[(size_t)gr * WD + c] : 0.f;
        }
        __syncthreads();
        float acc[4] = {0.f, 0.f, 0.f, 0.f};
        #pragma unroll 8
        for (int k = 0; k < WD; ++k) {
            float w = We[k * WD + j];
            acc[0] = fmaf(xs[q4 + 0][k], w, acc[0]);
            acc[1] = fmaf(xs[q4 + 4][k], w, acc[1]);
            acc[2] = fmaf(xs[q4 + 8][k], w, acc[2]);
            acc[3] = fmaf(xs[q4 + 12][k], w, acc[3]);
        }
        #pragma unroll
        for (int q = 0; q < 4; ++q) {
            int r = q4 + q * 4;
            int gr = row0 + r;
            if (gr < n) {
                unsigned p = bf16_rne(xs[r][j]) | (bf16_rne(acc[q]) << 16);
                xy[(size_t)gr * WD + j] = p;
            }
        }
    } else {
        int base = ((blockIdx.x - gb) * 512 + threadIdx.x) * 2;
        if (base + 2 <= E) {
            int2 a = *(const int2*)(ei + base);
            int2 b = *(const int2*)(ei + E + base);
            atomicAdd(&cnt[a.x], 1); atomicAdd(&cnt[b.x], 1);
            atomicAdd(&cnt[a.y], 1); atomicAdd(&cnt[b.y], 1);
        } else {
            for (int e = base; e < E; ++e) {
                atomicAdd(&cnt[ei[e]], 1);
                atomicAdd(&cnt[ei[E + e]], 1);
            }
        }
    }
}

__global__ __launch_bounds__(256) void k_chunksum(const int* __restrict__ cnt,
                                                  int* __restrict__ partials, int n) {
    __shared__ int ls[256];
    int t = threadIdx.x;
    int i = blockIdx.x * 256 + t;
    ls[t] = (i < n) ? cnt[i] : 0;
    __syncthreads();
    for (int s = 128; s > 0; s >>= 1) {
        if (t < s) ls[t] += ls[t + s];
        __syncthreads();
    }
    if (t == 0) partials[blockIdx.x] = ls[0];
}

__global__ __launch_bounds__(256) void k_scanpartials(int* __restrict__ partials,
                                                      int nchunks) {
    __shared__ int ls[256];
    int t = threadIdx.x;
    int v = (t < nchunks) ? partials[t] : 0;
    ls[t] = v;
    __syncthreads();
    for (int s = 1; s < 256; s <<= 1) {
        int tmp = (t >= s) ? ls[t - s] : 0;
        __syncthreads();
        ls[t] += tmp;
        __syncthreads();
    }
    if (t < nchunks) partials[t] = ls[t] - v;  // exclusive
}

__global__ __launch_bounds__(256) void k_chunkscan(const int* __restrict__ cnt,
                                                   const int* __restrict__ partials,
                                                   int* __restrict__ offsets,
                                                   int* __restrict__ cursors, int n) {
    __shared__ int ls[256];
    int t = threadIdx.x;
    int i = blockIdx.x * 256 + t;
    int v = (i < n) ? cnt[i] : 0;
    ls[t] = v;
    __syncthreads();
    for (int s = 1; s < 256; s <<= 1) {
        int tmp = (t >= s) ? ls[t - s] : 0;
        __syncthreads();
        ls[t] += tmp;
        __syncthreads();
    }
    int off = partials[blockIdx.x] + ls[t] - v;
    if (i < n) {
        offsets[i] = off;
        cursors[i] = off;
        if (i == n - 1) offsets[n] = off + v;
    }
}

// scatter: adjacency entry is 4 bytes: (edge_id << 1) | dir
// dir=0 -> dst = ei[E+eid] (nbr = ei[eid]); dir=1 -> dst = ei[eid] (nbr = ei[E+eid])
__global__ __launch_bounds__(256) void k_scatter(const int* __restrict__ ei,
                                                 int* __restrict__ cursors,
                                                 int* __restrict__ adj, int E) {
    int base = (blockIdx.x * 256 + threadIdx.x) * 4;
    if (base + 4 <= E) {
        int4 a = *(const int4*)(ei + base);
        int4 b = *(const int4*)(ei + E + base);
        int pb0 = atomicAdd(&cursors[b.x], 1);
        int pa0 = atomicAdd(&cursors[a.x], 1);
        int pb1 = atomicAdd(&cursors[b.y], 1);
        int pa1 = atomicAdd(&cursors[a.y], 1);
        int pb2 = atomicAdd(&cursors[b.z], 1);
        int pa2 = atomicAdd(&cursors[a.z], 1);
        int pb3 = atomicAdd(&cursors[b.w], 1);
        int pa3 = atomicAdd(&cursors[a.w], 1);
        adj[pb0] = ((base + 0) << 1);
        adj[pa0] = ((base + 0) << 1) | 1;
        adj[pb1] = ((base + 1) << 1);
        adj[pa1] = ((base + 1) << 1) | 1;
        adj[pb2] = ((base + 2) << 1);
        adj[pa2] = ((base + 2) << 1) | 1;
        adj[pb3] = ((base + 3) << 1);
        adj[pa3] = ((base + 3) << 1) | 1;
    } else {
        for (int e = base; e < E; ++e) {
            int aa = ei[e];
            int bb = ei[E + e];
            int p1 = atomicAdd(&cursors[bb], 1);
            adj[p1] = (e << 1);
            int p2 = atomicAdd(&cursors[aa], 1);
            adj[p2] = (e << 1) | 1;
        }
    }
}

// ============ node-parallel segment max; 4B adj entries; uniform s_loads ============
__global__ __launch_bounds__(128) void k_nodemax(const int* __restrict__ offsets,
                                                 const int* __restrict__ adj,
                                                 const int* __restrict__ ei,
                                                 const float2* __restrict__ ef,
                                                 const unsigned* __restrict__ xy,
                                                 const float* __restrict__ We,
                                                 const float* __restrict__ be,
                                                 float* __restrict__ mxstage,
                                                 int n, int E) {
    __shared__ int sh[128];
    int d = blockIdx.x;
    int j = threadIdx.x;
    int beg = offsets[d], end = offsets[d + 1];
    unsigned pd = xy[(size_t)d * WD + j];
    float xd = bf16_lo(pd), yd = bf16_hi(pd);
    float w0 = We[128 * WD + j];
    float w1 = We[129 * WD + j];
    float bj = be[j];
    float m = -INFINITY;
    for (int base = beg; base < end; base += 128) {
        int cnt = min(end - base, 128);
        if (j < cnt) sh[j] = adj[base + j];
        __syncthreads();
        int i = 0;
        for (; i + 4 <= cnt; i += 4) {
            int t0e = __builtin_amdgcn_readfirstlane(sh[i]);
            int t1e = __builtin_amdgcn_readfirstlane(sh[i + 1]);
            int t2e = __builtin_amdgcn_readfirstlane(sh[i + 2]);
            int t3e = __builtin_amdgcn_readfirstlane(sh[i + 3]);
            int id0 = t0e >> 1, id1 = t1e >> 1, id2 = t2e >> 1, id3 = t3e >> 1;
            int nb0 = ei[((t0e & 1) ? E : 0) + id0];
            int nb1 = ei[((t1e & 1) ? E : 0) + id1];
            int nb2 = ei[((t2e & 1) ? E : 0) + id2];
            int nb3 = ei[((t3e & 1) ? E : 0) + id3];
            float2 f0 = ef[id0], f1 = ef[id1], f2 = ef[id2], f3 = ef[id3];
            unsigned p0 = xy[(size_t)nb0 * WD + j];
            unsigned p1 = xy[(size_t)nb1 * WD + j];
            unsigned p2 = xy[(size_t)nb2 * WD + j];
            unsigned p3 = xy[(size_t)nb3 * WD + j];
            float c0 = fmaf(f0.x, w0, fmaf(f0.y, w1, bj));
            float c1 = fmaf(f1.x, w0, fmaf(f1.y, w1, bj));
            float c2 = fmaf(f2.x, w0, fmaf(f2.y, w1, bj));
            float c3 = fmaf(f3.x, w0, fmaf(f3.y, w1, bj));
            float u0 = (xd - bf16_lo(p0)) + fmaxf((yd - bf16_hi(p0)) + c0, 0.f);
            float u1 = (xd - bf16_lo(p1)) + fmaxf((yd - bf16_hi(p1)) + c1, 0.f);
            float u2 = (xd - bf16_lo(p2)) + fmaxf((yd - bf16_hi(p2)) + c2, 0.f);
            float u3 = (xd - bf16_lo(p3)) + fmaxf((yd - bf16_hi(p3)) + c3, 0.f);
            m = fmaxf(m, fmaxf(fmaxf(u0, u1), fmaxf(u2, u3)));
        }
        for (; i < cnt; ++i) {
            int t0e = __builtin_amdgcn_readfirstlane(sh[i]);
            int id0 = t0e >> 1;
            int nb0 = ei[((t0e & 1) ? E : 0) + id0];
            float2 f0 = ef[id0];
            unsigned p0 = xy[(size_t)nb0 * WD + j];
            float c0 = fmaf(f0.x, w0, fmaf(f0.y, w1, bj));
            m = fmaxf(m, (xd - bf16_lo(p0)) + fmaxf((yd - bf16_hi(p0)) + c0, 0.f));
        }
        __syncthreads();
    }
    mxstage[(size_t)d * WD + j] = (beg < end) ? m : 0.f;
}

// ============ out = x + relu([x, mx] @ Wm + b); mx staged in d_out ============
__global__ __launch_bounds__(512) void gemm_out(const float* __restrict__ x,
                                                const float* __restrict__ mx,
                                                const float* __restrict__ Wm,
                                                const float* __restrict__ b,
                                                float* __restrict__ out, int n) {
    __shared__ float xs[16][2 * WD];
    int j = threadIdx.x & 127;
    int q4 = threadIdx.x >> 7;  // 0..3
    int row0 = blockIdx.x * 16;
    for (int t = threadIdx.x; t < 16 * 2 * WD; t += 512) {
        int r = t >> 8, c = t & 255;
        int gr = row0 + r;
        float v = 0.f;
        if (gr < n) v = (c < WD) ? x[(size_t)gr * WD + c] : mx[(size_t)gr * WD + (c - WD)];
        xs[r][c] = v;
    }
    __syncthreads();
    float acc[4] = {0.f, 0.f, 0.f, 0.f};
    #pragma unroll 8
    for (int k = 0; k < 2 * WD; ++k) {
        float w = Wm[k * WD + j];
        acc[0] = fmaf(xs[q4 + 0][k], w, acc[0]);
        acc[1] = fmaf(xs[q4 + 4][k], w, acc[1]);
        acc[2] = fmaf(xs[q4 + 8][k], w, acc[2]);
        acc[3] = fmaf(xs[q4 + 12][k], w, acc[3]);
    }
    float bj = b[j];
    #pragma unroll
    for (int q = 0; q < 4; ++q) {
        int gr = row0 + q4 + q * 4;
        if (gr < n) {
            float xv = x[(size_t)gr * WD + j];
            out[(size_t)gr * WD + j] = xv + fmaxf(acc[q] + bj, 0.f);
        }
    }
}

extern "C" void kernel_launch(void* const* d_in, const int* in_sizes, int n_in,
                              void* d_out, int out_size, void* d_ws, size_t ws_size,
                              hipStream_t stream) {
    const float* x_p = (const float*)d_in[0];
    const int*   ei  = (const int*)d_in[1];
    const float* ef  = (const float*)d_in[2];
    const float* We  = (const float*)d_in[3];
    const float* be  = (const float*)d_in[4];
    const float* Wm  = (const float*)d_in[5];
    const float* bm  = (const float*)d_in[6];

    int n = in_sizes[0] / WD;   // 50000
    int E = in_sizes[1] / 2;    // 800000
    int E2 = 2 * E;

    // ---- workspace layout ----
    char* p = (char*)d_ws;
    unsigned* xy = (unsigned*)p;          p += (size_t)n * WD * sizeof(unsigned);  // 25.6 MB
    int* offsets = (int*)p;               p += ((size_t)(n + 1) * 4 + 15) & ~15ull;
    int* cursors = (int*)p;               p += ((size_t)n * 4 + 15) & ~15ull;
    int* partials = (int*)p;              p += 1024 * 4;
    int* adj = (int*)p;                   p += (size_t)E2 * 4;                     // 6.4 MB

    int nchunks = (n + 255) / 256;          // 196 (<= 256)
    int gb = (n + 15) / 16;                 // gemm blocks
    int cb = (E + 1023) / 1024;             // count blocks (512 thr x 2 edges)
    int ethreads4 = (E + 3) / 4;

    hipMemsetAsync(cursors, 0, (size_t)n * sizeof(int), stream);
    k_gemm_count<<<gb + cb, 512, 0, stream>>>(x_p, We, xy, ei, cursors, n, E, gb);
    k_chunksum<<<nchunks, 256, 0, stream>>>(cursors, partials, n);
    k_scanpartials<<<1, 256, 0, stream>>>(partials, nchunks);
    k_chunkscan<<<nchunks, 256, 0, stream>>>(cursors, partials, offsets, cursors, n);
    k_scatter<<<(ethreads4 + 255) / 256, 256, 0, stream>>>(ei, cursors, adj, E);

    k_nodemax<<<n, 128, 0, stream>>>(offsets, adj, ei, (const float2*)ef, xy,
                                     We, be, (float*)d_out, n, E);
    gemm_out<<<(n + 15) / 16, 512, 0, stream>>>(x_p, (const float*)d_out, Wm, bm,
                                                (float*)d_out, n);
}

// Round 7
// 473.756 us; speedup vs baseline: 1.0803x; 1.0803x over previous
//
#include <hip/hip_runtime.h>
#include <math.h>

#define WD 128

// ---- bf16 round-to-nearest-even, low 16 bits ----
__device__ __forceinline__ unsigned bf16_rne(float f) {
    unsigned u = __float_as_uint(f);
    return (u + 0x7FFFu + ((u >> 16) & 1u)) >> 16;
}
__device__ __forceinline__ float bf16_lo(unsigned p) {  // low bf16 -> f32
    return __uint_as_float(p << 16);
}
__device__ __forceinline__ float bf16_hi(unsigned p) {  // high bf16 -> f32
    return __uint_as_float(p & 0xFFFF0000u);
}

// ============ fused: [blocks < gb]  y = x @ We[:128]; pack {bf16 x, bf16 y}
//                     [blocks >= gb] degree count (2 edges/thread) ============
__global__ __launch_bounds__(512) void k_gemm_count(const float* __restrict__ x,
                                                    const float* __restrict__ We,
                                                    unsigned* __restrict__ xy,
                                                    const int* __restrict__ ei,
                                                    int* __restrict__ cnt,
                                                    int n, int E, int gb) {
    if ((int)blockIdx.x < gb) {
        __shared__ float xs[16][WD];
        int j = threadIdx.x & 127;
        int q4 = threadIdx.x >> 7;  // 0..3
        int row0 = blockIdx.x * 16;
        for (int t = threadIdx.x; t < 16 * WD; t += 512) {
            int r = t >> 7, c = t & 127;
            int gr = row0 + r;
            xs[r][c] = (gr < n) ? x[(size_t)gr * WD + c] : 0.f;
        }
        __syncthreads();
        float acc[4] = {0.f, 0.f, 0.f, 0.f};
        #pragma unroll 8
        for (int k = 0; k < WD; ++k) {
            float w = We[k * WD + j];
            acc[0] = fmaf(xs[q4 + 0][k], w, acc[0]);
            acc[1] = fmaf(xs[q4 + 4][k], w, acc[1]);
            acc[2] = fmaf(xs[q4 + 8][k], w, acc[2]);
            acc[3] = fmaf(xs[q4 + 12][k], w, acc[3]);
        }
        #pragma unroll
        for (int q = 0; q < 4; ++q) {
            int r = q4 + q * 4;
            int gr = row0 + r;
            if (gr < n) {
                unsigned p = bf16_rne(xs[r][j]) | (bf16_rne(acc[q]) << 16);
                xy[(size_t)gr * WD + j] = p;
            }
        }
    } else {
        int base = ((blockIdx.x - gb) * 512 + threadIdx.x) * 2;
        if (base + 2 <= E) {
            int2 a = *(const int2*)(ei + base);
            int2 b = *(const int2*)(ei + E + base);
            atomicAdd(&cnt[a.x], 1); atomicAdd(&cnt[b.x], 1);
            atomicAdd(&cnt[a.y], 1); atomicAdd(&cnt[b.y], 1);
        } else {
            for (int e = base; e < E; ++e) {
                atomicAdd(&cnt[ei[e]], 1);
                atomicAdd(&cnt[ei[E + e]], 1);
            }
        }
    }
}

__global__ __launch_bounds__(256) void k_chunksum(const int* __restrict__ cnt,
                                                  int* __restrict__ partials, int n) {
    __shared__ int ls[256];
    int t = threadIdx.x;
    int i = blockIdx.x * 256 + t;
    ls[t] = (i < n) ? cnt[i] : 0;
    __syncthreads();
    for (int s = 128; s > 0; s >>= 1) {
        if (t < s) ls[t] += ls[t + s];
        __syncthreads();
    }
    if (t == 0) partials[blockIdx.x] = ls[0];
}

__global__ __launch_bounds__(256) void k_scanpartials(int* __restrict__ partials,
                                                      int nchunks) {
    __shared__ int ls[256];
    int t = threadIdx.x;
    int v = (t < nchunks) ? partials[t] : 0;
    ls[t] = v;
    __syncthreads();
    for (int s = 1; s < 256; s <<= 1) {
        int tmp = (t >= s) ? ls[t - s] : 0;
        __syncthreads();
        ls[t] += tmp;
        __syncthreads();
    }
    if (t < nchunks) partials[t] = ls[t] - v;  // exclusive
}

__global__ __launch_bounds__(256) void k_chunkscan(const int* __restrict__ cnt,
                                                   const int* __restrict__ partials,
                                                   int* __restrict__ offsets,
                                                   int* __restrict__ cursors, int n) {
    __shared__ int ls[256];
    int t = threadIdx.x;
    int i = blockIdx.x * 256 + t;
    int v = (i < n) ? cnt[i] : 0;
    ls[t] = v;
    __syncthreads();
    for (int s = 1; s < 256; s <<= 1) {
        int tmp = (t >= s) ? ls[t - s] : 0;
        __syncthreads();
        ls[t] += tmp;
        __syncthreads();
    }
    int off = partials[blockIdx.x] + ls[t] - v;
    if (i < n) {
        offsets[i] = off;
        cursors[i] = off;
        if (i == n - 1) offsets[n] = off + v;
    }
}

// scatter: adjacency entry is 4 bytes: (edge_id << 1) | dir
// dir=0 -> dst = ei[E+eid] (nbr = ei[eid]); dir=1 -> dst = ei[eid] (nbr = ei[E+eid])
__global__ __launch_bounds__(256) void k_scatter(const int* __restrict__ ei,
                                                 int* __restrict__ cursors,
                                                 int* __restrict__ adj, int E) {
    int base = (blockIdx.x * 256 + threadIdx.x) * 4;
    if (base + 4 <= E) {
        int4 a = *(const int4*)(ei + base);
        int4 b = *(const int4*)(ei + E + base);
        int pb0 = atomicAdd(&cursors[b.x], 1);
        int pa0 = atomicAdd(&cursors[a.x], 1);
        int pb1 = atomicAdd(&cursors[b.y], 1);
        int pa1 = atomicAdd(&cursors[a.y], 1);
        int pb2 = atomicAdd(&cursors[b.z], 1);
        int pa2 = atomicAdd(&cursors[a.z], 1);
        int pb3 = atomicAdd(&cursors[b.w], 1);
        int pa3 = atomicAdd(&cursors[a.w], 1);
        adj[pb0] = ((base + 0) << 1);
        adj[pa0] = ((base + 0) << 1) | 1;
        adj[pb1] = ((base + 1) << 1);
        adj[pa1] = ((base + 1) << 1) | 1;
        adj[pb2] = ((base + 2) << 1);
        adj[pa2] = ((base + 2) << 1) | 1;
        adj[pb3] = ((base + 3) << 1);
        adj[pa3] = ((base + 3) << 1) | 1;
    } else {
        for (int e = base; e < E; ++e) {
            int aa = ei[e];
            int bb = ei[E + e];
            int p1 = atomicAdd(&cursors[bb], 1);
            adj[p1] = (e << 1);
            int p2 = atomicAdd(&cursors[aa], 1);
            adj[p2] = (e << 1) | 1;
        }
    }
}

// ============ node-parallel segment max; 4B adj entries resolved in the
// PARALLEL staging phase (each thread decodes one entry -> LDS {nbr, ef}) ============
__global__ __launch_bounds__(128) void k_nodemax(const int* __restrict__ offsets,
                                                 const int* __restrict__ adj,
                                                 const int* __restrict__ ei,
                                                 const float2* __restrict__ ef,
                                                 const unsigned* __restrict__ xy,
                                                 const float* __restrict__ We,
                                                 const float* __restrict__ be,
                                                 float* __restrict__ mxstage,
                                                 int n, int E) {
    __shared__ int2 sh[128];
    int d = blockIdx.x;
    int j = threadIdx.x;
    int beg = offsets[d], end = offsets[d + 1];
    unsigned pd = xy[(size_t)d * WD + j];
    float xd = bf16_lo(pd), yd = bf16_hi(pd);
    float w0 = We[128 * WD + j];
    float w1 = We[129 * WD + j];
    float bj = be[j];
    float m = -INFINITY;
    for (int base = beg; base < end; base += 128) {
        int cnt = min(end - base, 128);
        if (j < cnt) {
            int t = adj[base + j];
            int id = t >> 1;
            int nb = ei[((t & 1) ? E : 0) + id];
            float2 f = ef[id];
            int2 v;
            v.x = nb;
            v.y = (int)(bf16_rne(f.x) | (bf16_rne(f.y) << 16));
            sh[j] = v;
        }
        __syncthreads();
        int i = 0;
        for (; i + 4 <= cnt; i += 4) {
            int2 v0 = sh[i], v1 = sh[i + 1], v2 = sh[i + 2], v3 = sh[i + 3];
            unsigned p0 = xy[(size_t)v0.x * WD + j];
            unsigned p1 = xy[(size_t)v1.x * WD + j];
            unsigned p2 = xy[(size_t)v2.x * WD + j];
            unsigned p3 = xy[(size_t)v3.x * WD + j];
            unsigned e0 = (unsigned)v0.y, e1 = (unsigned)v1.y;
            unsigned e2 = (unsigned)v2.y, e3 = (unsigned)v3.y;
            float c0 = fmaf(bf16_lo(e0), w0, fmaf(bf16_hi(e0), w1, bj));
            float c1 = fmaf(bf16_lo(e1), w0, fmaf(bf16_hi(e1), w1, bj));
            float c2 = fmaf(bf16_lo(e2), w0, fmaf(bf16_hi(e2), w1, bj));
            float c3 = fmaf(bf16_lo(e3), w0, fmaf(bf16_hi(e3), w1, bj));
            float u0 = (xd - bf16_lo(p0)) + fmaxf((yd - bf16_hi(p0)) + c0, 0.f);
            float u1 = (xd - bf16_lo(p1)) + fmaxf((yd - bf16_hi(p1)) + c1, 0.f);
            float u2 = (xd - bf16_lo(p2)) + fmaxf((yd - bf16_hi(p2)) + c2, 0.f);
            float u3 = (xd - bf16_lo(p3)) + fmaxf((yd - bf16_hi(p3)) + c3, 0.f);
            m = fmaxf(m, fmaxf(fmaxf(u0, u1), fmaxf(u2, u3)));
        }
        for (; i < cnt; ++i) {
            int2 v0 = sh[i];
            unsigned p0 = xy[(size_t)v0.x * WD + j];
            unsigned e0 = (unsigned)v0.y;
            float c0 = fmaf(bf16_lo(e0), w0, fmaf(bf16_hi(e0), w1, bj));
            m = fmaxf(m, (xd - bf16_lo(p0)) + fmaxf((yd - bf16_hi(p0)) + c0, 0.f));
        }
        __syncthreads();
    }
    mxstage[(size_t)d * WD + j] = (beg < end) ? m : 0.f;
}

// ============ out = x + relu([x, mx] @ Wm + b); mx staged in d_out ============
__global__ __launch_bounds__(512) void gemm_out(const float* __restrict__ x,
                                                const float* __restrict__ mx,
                                                const float* __restrict__ Wm,
                                                const float* __restrict__ b,
                                                float* __restrict__ out, int n) {
    __shared__ float xs[16][2 * WD];
    int j = threadIdx.x & 127;
    int q4 = threadIdx.x >> 7;  // 0..3
    int row0 = blockIdx.x * 16;
    for (int t = threadIdx.x; t < 16 * 2 * WD; t += 512) {
        int r = t >> 8, c = t & 255;
        int gr = row0 + r;
        float v = 0.f;
        if (gr < n) v = (c < WD) ? x[(size_t)gr * WD + c] : mx[(size_t)gr * WD + (c - WD)];
        xs[r][c] = v;
    }
    __syncthreads();
    float acc[4] = {0.f, 0.f, 0.f, 0.f};
    #pragma unroll 8
    for (int k = 0; k < 2 * WD; ++k) {
        float w = Wm[k * WD + j];
        acc[0] = fmaf(xs[q4 + 0][k], w, acc[0]);
        acc[1] = fmaf(xs[q4 + 4][k], w, acc[1]);
        acc[2] = fmaf(xs[q4 + 8][k], w, acc[2]);
        acc[3] = fmaf(xs[q4 + 12][k], w, acc[3]);
    }
    float bj = b[j];
    #pragma unroll
    for (int q = 0; q < 4; ++q) {
        int gr = row0 + q4 + q * 4;
        if (gr < n) {
            float xv = x[(size_t)gr * WD + j];
            out[(size_t)gr * WD + j] = xv + fmaxf(acc[q] + bj, 0.f);
        }
    }
}

extern "C" void kernel_launch(void* const* d_in, const int* in_sizes, int n_in,
                              void* d_out, int out_size, void* d_ws, size_t ws_size,
                              hipStream_t stream) {
    const float* x_p = (const float*)d_in[0];
    const int*   ei  = (const int*)d_in[1];
    const float* ef  = (const float*)d_in[2];
    const float* We  = (const float*)d_in[3];
    const float* be  = (const float*)d_in[4];
    const float* Wm  = (const float*)d_in[5];
    const float* bm  = (const float*)d_in[6];

    int n = in_sizes[0] / WD;   // 50000
    int E = in_sizes[1] / 2;    // 800000
    int E2 = 2 * E;

    // ---- workspace layout ----
    char* p = (char*)d_ws;
    unsigned* xy = (unsigned*)p;          p += (size_t)n * WD * sizeof(unsigned);  // 25.6 MB
    int* offsets = (int*)p;               p += ((size_t)(n + 1) * 4 + 15) & ~15ull;
    int* cursors = (int*)p;               p += ((size_t)n * 4 + 15) & ~15ull;
    int* partials = (int*)p;              p += 1024 * 4;
    int* adj = (int*)p;                   p += (size_t)E2 * 4;                     // 6.4 MB

    int nchunks = (n + 255) / 256;          // 196 (<= 256)
    int gb = (n + 15) / 16;                 // gemm blocks
    int cb = (E + 1023) / 1024;             // count blocks (512 thr x 2 edges)
    int ethreads4 = (E + 3) / 4;

    hipMemsetAsync(cursors, 0, (size_t)n * sizeof(int), stream);
    k_gemm_count<<<gb + cb, 512, 0, stream>>>(x_p, We, xy, ei, cursors, n, E, gb);
    k_chunksum<<<nchunks, 256, 0, stream>>>(cursors, partials, n);
    k_scanpartials<<<1, 256, 0, stream>>>(partials, nchunks);
    k_chunkscan<<<nchunks, 256, 0, stream>>>(cursors, partials, offsets, cursors, n);
    k_scatter<<<(ethreads4 + 255) / 256, 256, 0, stream>>>(ei, cursors, adj, E);

    k_nodemax<<<n, 128, 0, stream>>>(offsets, adj, ei, (const float2*)ef, xy,
                                     We, be, (float*)d_out, n, E);
    gemm_out<<<(n + 15) / 16, 512, 0, stream>>>(x_p, (const float*)d_out, Wm, bm,
                                                (float*)d_out, n);
}